// Round 3
// baseline (93.899 us; speedup 1.0000x reference)
//
#include <hip/hip_runtime.h>
#include <hip/hip_bf16.h>
#include <math.h>

#define DEMBED 512
#define NTOK   (64 * 1024)
#define TPB    256
#define BLOCKS 2048
#define STRIDE (BLOCKS * TPB)          // 524288 threads
#define N4     (NTOK * (DEMBED / 4))   // 8388608 float4 elements
#define ITERS  (N4 / STRIDE)           // exactly 16
#define NBUCK  512                     // bucket = row >> 6 (500 used, padded)

typedef float f4 __attribute__((ext_vector_type(4)));

// ---------- pass 0: zero bucket counters ----------
__global__ void zero_kernel(int* __restrict__ counts) {
    counts[threadIdx.x] = 0;                       // <<<1, NBUCK>>>
}

// ---------- pass 1: histogram of row-buckets ----------
__global__ void hist_kernel(const int* __restrict__ x, int* __restrict__ counts) {
    int t = blockIdx.x * blockDim.x + threadIdx.x; // 65536 threads
    atomicAdd(&counts[x[t] >> 6], 1);
}

// ---------- pass 2: exclusive scan -> cursors ----------
__global__ void scan_kernel(const int* __restrict__ counts, int* __restrict__ cursors) {
    __shared__ int buf[2][NBUCK];
    int tid = threadIdx.x;                         // <<<1, NBUCK>>>
    int my  = counts[tid];
    buf[0][tid] = my;
    __syncthreads();
    int src = 0;
    for (int d = 1; d < NBUCK; d <<= 1) {
        int v = buf[src][tid];
        if (tid >= d) v += buf[src][tid - d];
        buf[src ^ 1][tid] = v;
        src ^= 1;
        __syncthreads();
    }
    cursors[tid] = buf[src][tid] - my;             // exclusive prefix
}

// ---------- pass 3: scatter token ids into bucket-sorted order ----------
__global__ void scatter_kernel(const int* __restrict__ x, int* __restrict__ cursors,
                               int* __restrict__ perm) {
    int t = blockIdx.x * blockDim.x + threadIdx.x; // 65536 threads
    int b = x[t] >> 6;
    int p = atomicAdd(&cursors[b], 1);             // intra-bucket order arbitrary: output-invariant
    perm[p] = t;
}

// ---------- pass 4: gather + positional add, tokens in row-sorted order ----------
__global__ void __launch_bounds__(TPB)
embed_kernel(const int* __restrict__ x,
             const int* __restrict__ perm,
             const float* __restrict__ table,
             float* __restrict__ out)
{
    const int tid = blockIdx.x * TPB + threadIdx.x;
    const int d4  = tid & 127;                     // float4 column, fixed per thread

    // inline positional embedding for this thread's 4 columns (one-time)
    f4 p;
    const float kLog = logf(10000.0f) / (float)DEMBED;
#pragma unroll
    for (int j = 0; j < 4; ++j) {
        int   i      = d4 * 4 + j;
        float ep_idx = (float)(i & ~1);            // even index duplicated to odd
        float ep     = expf(-ep_idx * kLog);       // 10000^(-ep_idx/512)
        float ang    = (float)i * ep;
        p[j] = (i & 1) ? cosf(ang) : sinf(ang);
    }

    const f4* __restrict__ t4 = (const f4*)table;
    f4*       __restrict__ o4 = (f4*)out;

#pragma unroll
    for (int it = 0; it < ITERS; ++it) {
        int gid  = tid + it * STRIDE;
        int slot = gid >> 7;                       // processing slot (row-sorted)
        int tok  = perm[slot];                     // wave-uniform load
        int row  = x[tok];                         // wave-uniform load
        f4  t    = t4[(size_t)row * 128 + d4];     // near-sequential table sweep, dup rows adjacent
        f4  r    = t + p;
        __builtin_nontemporal_store(r, &o4[(size_t)tok * 128 + d4]);  // 2KB-granule scatter
    }
}

extern "C" void kernel_launch(void* const* d_in, const int* in_sizes, int n_in,
                              void* d_out, int out_size, void* d_ws, size_t ws_size,
                              hipStream_t stream) {
    const int*   x     = (const int*)d_in[0];      // [64,1024] token ids
    const float* table = (const float*)d_in[1];    // [32000,512]
    float*       out   = (float*)d_out;            // [64,1024,512]

    int* counts  = (int*)d_ws;                     // [NBUCK]
    int* cursors = counts + NBUCK;                 // [NBUCK]
    int* perm    = cursors + NBUCK;                // [NTOK]

    zero_kernel   <<<1, NBUCK, 0, stream>>>(counts);
    hist_kernel   <<<NTOK / TPB, TPB, 0, stream>>>(x, counts);
    scan_kernel   <<<1, NBUCK, 0, stream>>>(counts, cursors);
    scatter_kernel<<<NTOK / TPB, TPB, 0, stream>>>(x, cursors, perm);
    embed_kernel  <<<BLOCKS, TPB, 0, stream>>>(x, perm, table, out);
}

// Round 4
// 44.174 us; speedup vs baseline: 2.1257x; 2.1257x over previous
//
#include <hip/hip_runtime.h>
#include <hip/hip_bf16.h>
#include <math.h>

#define DEMBED 512
#define NTOK   (64 * 1024)
#define TPB    256
#define BLOCKS 2048
#define WAVES  (BLOCKS * TPB / 64)     // 8192 waves
#define TPW    (NTOK / WAVES)          // 8 tokens per wave

typedef float f4 __attribute__((ext_vector_type(4)));

// One wave owns one token row (2 KB) per iteration: lane covers 16 B at
// byte offsets lane*16 and lane*16+1024. Index loads are scalarized via
// readfirstlane so the scalar unit runs ahead of the vector gather.
__global__ void __launch_bounds__(TPB)
embed_kernel(const int* __restrict__ x,
             const float* __restrict__ table,
             float* __restrict__ out)
{
    const int lane = threadIdx.x & 63;
    int wave = (blockIdx.x * TPB + threadIdx.x) >> 6;
    wave = __builtin_amdgcn_readfirstlane(wave);   // SGPR wave id
    const int tok0 = wave * TPW;

    // ---- positional values for this lane's two float4 slots ----
    // slot A: columns [lane*4, lane*4+4)   slot B: columns [256+lane*4, ...)
    f4 pA, pB;
    const float kLog = logf(10000.0f) / (float)DEMBED;
#pragma unroll
    for (int j = 0; j < 4; ++j) {
        int   ia  = lane * 4 + j;
        float ea  = expf(-(float)(ia & ~1) * kLog);
        float aa  = (float)ia * ea;
        pA[j] = (ia & 1) ? cosf(aa) : sinf(aa);
        int   ib  = 256 + lane * 4 + j;
        float eb  = expf(-(float)(ib & ~1) * kLog);
        float ab  = (float)ib * eb;
        pB[j] = (ib & 1) ? cosf(ab) : sinf(ab);
    }

    // ---- scalar index loads, issued up front ----
    int rows[TPW];
#pragma unroll
    for (int i = 0; i < TPW; ++i)
        rows[i] = x[tok0 + i];                     // uniform addr -> s_load

    // ---- 16 independent table loads in flight ----
#pragma unroll
    for (int i = 0; i < TPW; ++i) {
        const f4* __restrict__ src = (const f4*)(table + (size_t)rows[i] * DEMBED);
        f4 a = src[lane];                          // first 1 KB of row
        f4 b = src[lane + 64];                     // second 1 KB
        f4 ra = a + pA;
        f4 rb = b + pB;
        f4* __restrict__ dst = (f4*)(out + (size_t)(tok0 + i) * DEMBED);
        __builtin_nontemporal_store(ra, &dst[lane]);
        __builtin_nontemporal_store(rb, &dst[lane + 64]);
    }
}

extern "C" void kernel_launch(void* const* d_in, const int* in_sizes, int n_in,
                              void* d_out, int out_size, void* d_ws, size_t ws_size,
                              hipStream_t stream) {
    const int*   x     = (const int*)d_in[0];      // [64,1024] token ids
    const float* table = (const float*)d_in[1];    // [32000,512]
    float*       out   = (float*)d_out;            // [64,1024,512]

    embed_kernel<<<BLOCKS, TPB, 0, stream>>>(x, table, out);
}